// Round 1
// baseline (369.329 us; speedup 1.0000x reference)
//
#include <hip/hip_runtime.h>

// Problem constants (match reference setup_inputs)
constexpr int B       = 4;
constexpr int N_NODES = 1000000;
constexpr int N_ELEM  = 500000;
constexpr int N_GP    = 9;
constexpr int N_EN    = 8;

// out[b][(e*N_GP+g)][c], c in {e_xx, e_yy, e_xy}
// e_xx = sum_k shpdx[e,g,k,0] * inp[b, nd[k], 0]
// e_yy = sum_k shpdx[e,g,k,1] * inp[b, nd[k], 1]
// e_xy = 0.5 * sum_k (shpdx[e,g,k,1]*inp[b,nd[k],0] + shpdx[e,g,k,0]*inp[b,nd[k],1])
__global__ __launch_bounds__(256) void kinematic_kernel(
    const float* __restrict__ inputs,   // [B][N_NODES][2]
    const float* __restrict__ shpdx,    // [N_ELEM][N_GP][N_EN][2]
    const int*   __restrict__ elem,     // [N_ELEM][N_EN]
    float*       __restrict__ out)      // [B][N_ELEM*N_GP][3]
{
    const int total = N_ELEM * N_GP;           // 4.5M
    int tid = blockIdx.x * blockDim.x + threadIdx.x;
    if (tid >= total) return;

    int e = tid / N_GP;                        // compiler emits magic-mul
    // g = tid - e*N_GP (implicit via tid addressing below)

    // ---- shpdx[e][g][k][l]: 16 contiguous floats, 64B-aligned ----
    const float4* sp = reinterpret_cast<const float4*>(shpdx) + (size_t)tid * 4;
    float4 s0 = sp[0];
    float4 s1 = sp[1];
    float4 s2 = sp[2];
    float4 s3 = sp[3];
    float sx[8], sy[8];
    sx[0]=s0.x; sy[0]=s0.y;  sx[1]=s0.z; sy[1]=s0.w;
    sx[2]=s1.x; sy[2]=s1.y;  sx[3]=s1.z; sy[3]=s1.w;
    sx[4]=s2.x; sy[4]=s2.y;  sx[5]=s2.z; sy[5]=s2.w;
    sx[6]=s3.x; sy[6]=s3.y;  sx[7]=s3.z; sy[7]=s3.w;

    // ---- elem_nodes[e][0..7]: 32B, shared by the 9 gp-threads of element e ----
    const int4* ep = reinterpret_cast<const int4*>(elem + (size_t)e * N_EN);
    int4 n0 = ep[0];
    int4 n1 = ep[1];
    int nd[8] = { n0.x, n0.y, n0.z, n0.w, n1.x, n1.y, n1.z, n1.w };

    #pragma unroll
    for (int b = 0; b < B; ++b) {
        const float2* inb = reinterpret_cast<const float2*>(inputs) + (size_t)b * N_NODES;
        // issue all 8 gathers up front so latency overlaps
        float2 d[8];
        #pragma unroll
        for (int k = 0; k < 8; ++k) d[k] = inb[nd[k]];

        float axx = 0.f, ayy = 0.f, axy = 0.f;
        #pragma unroll
        for (int k = 0; k < 8; ++k) {
            axx = fmaf(sx[k], d[k].x, axx);
            ayy = fmaf(sy[k], d[k].y, ayy);
            axy = fmaf(sy[k], d[k].x, fmaf(sx[k], d[k].y, axy));
        }

        size_t o = ((size_t)b * total + (size_t)tid) * 3;
        out[o + 0] = axx;
        out[o + 1] = ayy;
        out[o + 2] = 0.5f * axy;
    }
}

extern "C" void kernel_launch(void* const* d_in, const int* in_sizes, int n_in,
                              void* d_out, int out_size, void* d_ws, size_t ws_size,
                              hipStream_t stream) {
    const float* inputs = (const float*)d_in[0];  // [B, N_NODES, 2]
    const float* shpdx  = (const float*)d_in[1];  // [N_ELEM, N_GP, 8, 2]
    const int*   elem   = (const int*)d_in[2];    // [N_ELEM, 8]
    float* out = (float*)d_out;                   // [B, N_ELEM*N_GP, 3]

    const int total = N_ELEM * N_GP;              // 4,500,000 threads
    const int block = 256;
    const int grid  = (total + block - 1) / block;
    kinematic_kernel<<<grid, block, 0, stream>>>(inputs, shpdx, elem, out);
}

// Round 2
// 163.866 us; speedup vs baseline: 2.2538x; 2.2538x over previous
//
#include <hip/hip_runtime.h>

// Problem constants (match reference setup_inputs)
constexpr int B       = 4;
constexpr int N_NODES = 1000000;
constexpr int N_ELEM  = 500000;
constexpr int N_GP    = 9;
constexpr int N_EN    = 8;

// ---------------------------------------------------------------------------
// Pass 1: transpose inputs [B][N_NODES][2] -> tn [N_NODES][B][2] (32B/node)
// so one node gather pulls all 4 batches in a single 32B (half-line) request.
// ---------------------------------------------------------------------------
__global__ __launch_bounds__(256) void transpose_nodes(
    const float* __restrict__ inputs,  // [B][N_NODES][2]
    float*       __restrict__ tn)      // [N_NODES][8] floats
{
    int n = blockIdx.x * blockDim.x + threadIdx.x;
    if (n >= N_NODES) return;
    const float2* in2 = reinterpret_cast<const float2*>(inputs);
    float2 a0 = in2[0 * (size_t)N_NODES + n];
    float2 a1 = in2[1 * (size_t)N_NODES + n];
    float2 a2 = in2[2 * (size_t)N_NODES + n];
    float2 a3 = in2[3 * (size_t)N_NODES + n];
    float4* t4 = reinterpret_cast<float4*>(tn) + (size_t)n * 2;
    t4[0] = make_float4(a0.x, a0.y, a1.x, a1.y);
    t4[1] = make_float4(a2.x, a2.y, a3.x, a3.y);
}

// ---------------------------------------------------------------------------
// Pass 2: one thread per (element, gauss point), all 4 batches per thread.
// ---------------------------------------------------------------------------
__global__ __launch_bounds__(256) void kinematic_t(
    const float4* __restrict__ tn,     // [N_NODES][2] float4
    const float*  __restrict__ shpdx,  // [N_ELEM][N_GP][N_EN][2]
    const int*    __restrict__ elem,   // [N_ELEM][N_EN]
    float*        __restrict__ out)    // [B][N_ELEM*N_GP][3]
{
    const int total = N_ELEM * N_GP;   // 4.5M
    int tid = blockIdx.x * blockDim.x + threadIdx.x;
    if (tid >= total) return;

    int e = tid / N_GP;

    // elem_nodes[e][0..7] — 32B, shared by the 9 gp-threads of element e
    const int4* ep = reinterpret_cast<const int4*>(elem + (size_t)e * N_EN);
    int4 n0 = ep[0];
    int4 n1 = ep[1];
    int nd[8] = { n0.x, n0.y, n0.z, n0.w, n1.x, n1.y, n1.z, n1.w };

    // Gather all 4 batches per node in one 32B record (2x float4).
    float4 lo[8], hi[8];
    #pragma unroll
    for (int k = 0; k < 8; ++k) {
        const float4* p = tn + (size_t)nd[k] * 2;
        lo[k] = p[0];   // b0.x b0.y b1.x b1.y
        hi[k] = p[1];   // b2.x b2.y b3.x b3.y
    }

    // shpdx[e][g][k][l]: 16 contiguous floats, 64B aligned
    const float4* sp = reinterpret_cast<const float4*>(shpdx) + (size_t)tid * 4;
    float4 s0 = sp[0];
    float4 s1 = sp[1];
    float4 s2 = sp[2];
    float4 s3 = sp[3];
    float sx[8] = { s0.x, s0.z, s1.x, s1.z, s2.x, s2.z, s3.x, s3.z };
    float sy[8] = { s0.y, s0.w, s1.y, s1.w, s2.y, s2.w, s3.y, s3.w };

    float axx[B] = {0.f, 0.f, 0.f, 0.f};
    float ayy[B] = {0.f, 0.f, 0.f, 0.f};
    float axy[B] = {0.f, 0.f, 0.f, 0.f};

    #pragma unroll
    for (int k = 0; k < 8; ++k) {
        float dx[B] = { lo[k].x, lo[k].z, hi[k].x, hi[k].z };
        float dy[B] = { lo[k].y, lo[k].w, hi[k].y, hi[k].w };
        #pragma unroll
        for (int b = 0; b < B; ++b) {
            axx[b] = fmaf(sx[k], dx[b], axx[b]);
            ayy[b] = fmaf(sy[k], dy[b], ayy[b]);
            axy[b] = fmaf(sy[k], dx[b], fmaf(sx[k], dy[b], axy[b]));
        }
    }

    #pragma unroll
    for (int b = 0; b < B; ++b) {
        size_t o = ((size_t)b * total + (size_t)tid) * 3;
        out[o + 0] = axx[b];
        out[o + 1] = ayy[b];
        out[o + 2] = 0.5f * axy[b];
    }
}

// ---------------------------------------------------------------------------
// Fallback (no-workspace path): R0 kernel, gathers from original layout.
// ---------------------------------------------------------------------------
__global__ __launch_bounds__(256) void kinematic_kernel(
    const float* __restrict__ inputs,
    const float* __restrict__ shpdx,
    const int*   __restrict__ elem,
    float*       __restrict__ out)
{
    const int total = N_ELEM * N_GP;
    int tid = blockIdx.x * blockDim.x + threadIdx.x;
    if (tid >= total) return;

    int e = tid / N_GP;

    const float4* sp = reinterpret_cast<const float4*>(shpdx) + (size_t)tid * 4;
    float4 s0 = sp[0];
    float4 s1 = sp[1];
    float4 s2 = sp[2];
    float4 s3 = sp[3];
    float sx[8] = { s0.x, s0.z, s1.x, s1.z, s2.x, s2.z, s3.x, s3.z };
    float sy[8] = { s0.y, s0.w, s1.y, s1.w, s2.y, s2.w, s3.y, s3.w };

    const int4* ep = reinterpret_cast<const int4*>(elem + (size_t)e * N_EN);
    int4 n0 = ep[0];
    int4 n1 = ep[1];
    int nd[8] = { n0.x, n0.y, n0.z, n0.w, n1.x, n1.y, n1.z, n1.w };

    #pragma unroll
    for (int b = 0; b < B; ++b) {
        const float2* inb = reinterpret_cast<const float2*>(inputs) + (size_t)b * N_NODES;
        float2 d[8];
        #pragma unroll
        for (int k = 0; k < 8; ++k) d[k] = inb[nd[k]];

        float axx = 0.f, ayy = 0.f, axy = 0.f;
        #pragma unroll
        for (int k = 0; k < 8; ++k) {
            axx = fmaf(sx[k], d[k].x, axx);
            ayy = fmaf(sy[k], d[k].y, ayy);
            axy = fmaf(sy[k], d[k].x, fmaf(sx[k], d[k].y, axy));
        }

        size_t o = ((size_t)b * total + (size_t)tid) * 3;
        out[o + 0] = axx;
        out[o + 1] = ayy;
        out[o + 2] = 0.5f * axy;
    }
}

extern "C" void kernel_launch(void* const* d_in, const int* in_sizes, int n_in,
                              void* d_out, int out_size, void* d_ws, size_t ws_size,
                              hipStream_t stream) {
    const float* inputs = (const float*)d_in[0];  // [B, N_NODES, 2]
    const float* shpdx  = (const float*)d_in[1];  // [N_ELEM, N_GP, 8, 2]
    const int*   elem   = (const int*)d_in[2];    // [N_ELEM, 8]
    float* out = (float*)d_out;                   // [B, N_ELEM*N_GP, 3]

    const int total = N_ELEM * N_GP;              // 4,500,000 threads
    const int block = 256;
    const int grid  = (total + block - 1) / block;

    const size_t tn_bytes = (size_t)N_NODES * B * 2 * sizeof(float); // 32 MB

    if (ws_size >= tn_bytes) {
        float* tn = (float*)d_ws;
        transpose_nodes<<<(N_NODES + block - 1) / block, block, 0, stream>>>(inputs, tn);
        kinematic_t<<<grid, block, 0, stream>>>(
            reinterpret_cast<const float4*>(tn), shpdx, elem, out);
    } else {
        kinematic_kernel<<<grid, block, 0, stream>>>(inputs, shpdx, elem, out);
    }
}